// Round 2
// baseline (5521.664 us; speedup 1.0000x reference)
//
#include <hip/hip_runtime.h>
#include <hip/hip_bf16.h>

// Problem: B=2048, D=256, H=266, S=50 steps. All inputs f32, output f32 [2048].
// Per step: P1 gemm+stats, P2 affine-relu-gemm+stats,
// P3 affine-relu-gemm + rowwise update of v, xc.

#define BATCH 2048
#define DD    256
#define HH    266
#define HP    272     // padded row stride for Y buffers
#define SS    50
#define BN_EPS 1e-5f
#define SIG   0.3f

// workspace layout (float offsets)
#define XC_OFF 0              // [2048][256]
#define Y1_OFF 524288         // [2048][272]
#define Y2_OFF 1081344        // [2048][272]
#define V_OFF  1638400        // [2048]
#define S1_OFF 1640448        // [2 parity][8 reps][544] (sum@+j, sq@+272+j)
#define S2_OFF 1649152        // same
#define SV_OFF 1657856        // [16] (v0 layer-3 scalar stats)
// total floats 1657872 (~6.6 MB)

// ---------------- init: xc = x, zero all stat buffers ----------------
__global__ __launch_bounds__(256) void k_init(const float* __restrict__ x,
                                              float* __restrict__ ws) {
    int idx = blockIdx.x * 256 + threadIdx.x;
    if (idx < BATCH * DD) {
        ws[XC_OFF + idx] = x[idx];
    } else {
        int z = idx - BATCH * DD;
        if (z < 17424) ws[S1_OFF + z] = 0.0f;   // S1(8704)+S2(8704)+SV(16)
    }
}

// BN affine constants a[k], c[k]: A = relu(a*y + c)
__device__ __forceinline__ void compute_ac(const float* __restrict__ stats_in,
                                           const float* __restrict__ g,
                                           const float* __restrict__ be,
                                           float (*AC)[HP]) {
    for (int t = threadIdx.x; t < HP; t += 256) {
        float a = 0.f, c = 0.f;
        if (t < HH) {
            float s = 0.f, q = 0.f;
            #pragma unroll
            for (int r = 0; r < 8; ++r) {
                s += stats_in[r * 544 + t];
                q += stats_in[r * 544 + 272 + t];
            }
            float mu  = s * (1.0f / 2048.0f);
            float var = q * (1.0f / 2048.0f) - mu * mu;
            float rs  = rsqrtf(fmaxf(var, 0.0f) + BN_EPS);
            a = g[t] * rs;
            c = be[t] - mu * a;
        }
        AC[0][t] = a;
        AC[1][t] = c;
    }
}

// ---------------- GEMM (N=266) + column stats ----------------
// mode 1: xsrc f32 raw; mode 2: xsrc f32 Y + affine-relu.
// Block = 2 rows, 4 waves split K; grid = 1024.
__global__ __launch_bounds__(256) void k_gemm(
    int mode, int K,
    const float* __restrict__ xsrc, int xld,
    const float* __restrict__ stats_in,
    const float* __restrict__ gv, const float* __restrict__ bev,
    const float* __restrict__ W, const float* __restrict__ bias,
    float* __restrict__ yout, float* __restrict__ stats_out,
    float* __restrict__ zero_ptr)
{
    __shared__ float Xs[2][HP];
    __shared__ float AC[2][HP];
    __shared__ float red[4][2][320];
    const int tid  = threadIdx.x;
    const int lane = tid & 63;
    const int tr   = tid >> 6;
    const int row0 = blockIdx.x * 2;

    // zero the opposite-parity stats buffer (4352 floats across blocks 0..16)
    if (zero_ptr != nullptr && blockIdx.x < 17)
        zero_ptr[blockIdx.x * 256 + tid] = 0.0f;

    if (mode == 2) {
        compute_ac(stats_in, gv, bev, AC);
        __syncthreads();
        for (int i = tid; i < 2 * HH; i += 256) {
            int r = (i >= HH) ? 1 : 0;
            int k = i - r * HH;
            float y = xsrc[(row0 + r) * xld + k];
            Xs[r][k] = fmaxf(fmaf(AC[0][k], y, AC[1][k]), 0.0f);
        }
    } else {
        for (int i = tid; i < 2 * K; i += 256) {
            int r = i / K, k = i - r * K;
            Xs[r][k] = xsrc[(row0 + r) * xld + k];
        }
    }
    __syncthreads();

    const int lo = (K * tr) >> 2;
    const int hi = (K * (tr + 1)) >> 2;
    // 5th column group: j = 256+lane valid for lane<10; others read j=0 (junk, discarded)
    const int joff4 = (lane < HH - 256) ? (256 + lane) : 0;

    float a00=0,a01=0,a02=0,a03=0,a04=0;
    float a10=0,a11=0,a12=0,a13=0,a14=0;
    const float* wp  = W + lo * HH + lane;
    const float* wp4 = W + lo * HH + joff4;
    for (int k = lo; k < hi; ++k) {
        float xa = Xs[0][k];
        float xb = Xs[1][k];
        float w0 = wp[0];
        float w1 = wp[64];
        float w2 = wp[128];
        float w3 = wp[192];
        float w4 = wp4[0];
        a00 = fmaf(xa, w0, a00); a10 = fmaf(xb, w0, a10);
        a01 = fmaf(xa, w1, a01); a11 = fmaf(xb, w1, a11);
        a02 = fmaf(xa, w2, a02); a12 = fmaf(xb, w2, a12);
        a03 = fmaf(xa, w3, a03); a13 = fmaf(xb, w3, a13);
        a04 = fmaf(xa, w4, a04); a14 = fmaf(xb, w4, a14);
        wp  += HH;
        wp4 += HH;
    }
    red[tr][0][lane]       = a00;
    red[tr][0][lane + 64]  = a01;
    red[tr][0][lane + 128] = a02;
    red[tr][0][lane + 192] = a03;
    red[tr][0][lane + 256] = a04;
    red[tr][1][lane]       = a10;
    red[tr][1][lane + 64]  = a11;
    red[tr][1][lane + 128] = a12;
    red[tr][1][lane + 192] = a13;
    red[tr][1][lane + 256] = a14;
    __syncthreads();

    float* sp = stats_out + (blockIdx.x & 7) * 544;
    for (int j = tid; j < 320; j += 256) {
        if (j >= HH) continue;
        float bj = bias[j];
        float v0 = red[0][0][j] + red[1][0][j] + red[2][0][j] + red[3][0][j] + bj;
        float v1 = red[0][1][j] + red[1][1][j] + red[2][1][j] + red[3][1][j] + bj;
        yout[row0 * HP + j]       = v0;
        yout[(row0 + 1) * HP + j] = v1;
        atomicAdd(sp + j, v0 + v1);
        atomicAdd(sp + 272 + j, v0 * v0 + v1 * v1);
    }
}

// ---------------- P3: grad = A2@W3+b3 (N=256), then v/xc update ----------------
// Block = 4 rows, 4 waves split K; grid = 512.
__global__ __launch_bounds__(256) void k_step3(
    const float* __restrict__ y2, const float* __restrict__ stats_in,
    const float* __restrict__ gv, const float* __restrict__ bev,
    const float* __restrict__ W3, const float* __restrict__ b3,
    const float* __restrict__ law, const float* __restrict__ dWs,
    const float* __restrict__ tg, int s,
    float* __restrict__ xc, float* __restrict__ vv,
    float* __restrict__ out)
{
    __shared__ float AC[2][HP];
    __shared__ float Xs[4][HP];
    __shared__ float red[4][4][256];
    const int tid  = threadIdx.x;
    const int lane = tid & 63;
    const int tr   = tid >> 6;
    const int row0 = blockIdx.x * 4;

    compute_ac(stats_in, gv, bev, AC);
    __syncthreads();
    for (int i = tid; i < 4 * HH; i += 256) {
        int r = i / HH;
        int k = i - r * HH;
        float y = y2[(row0 + r) * HP + k];
        Xs[r][k] = fmaxf(fmaf(AC[0][k], y, AC[1][k]), 0.0f);
    }
    __syncthreads();

    const int lo = (HH * tr) >> 2;
    const int hi = (HH * (tr + 1)) >> 2;
    float acc[4][4] = {};
    const float* wp = W3 + lo * DD + lane;
    for (int k = lo; k < hi; ++k) {
        float w0 = wp[0];
        float w1 = wp[64];
        float w2 = wp[128];
        float w3 = wp[192];
        #pragma unroll
        for (int r = 0; r < 4; ++r) {
            float xr = Xs[r][k];
            acc[r][0] = fmaf(xr, w0, acc[r][0]);
            acc[r][1] = fmaf(xr, w1, acc[r][1]);
            acc[r][2] = fmaf(xr, w2, acc[r][2]);
            acc[r][3] = fmaf(xr, w3, acc[r][3]);
        }
        wp += DD;
    }
    #pragma unroll
    for (int r = 0; r < 4; ++r) {
        red[tr][r][lane]       = acc[r][0];
        red[tr][r][lane + 64]  = acc[r][1];
        red[tr][r][lane + 128] = acc[r][2];
        red[tr][r][lane + 192] = acc[r][3];
    }
    __syncthreads();

    {
        const int r   = tr;          // wave tr owns row tr of the 4-row slab
        const int row = row0 + r;
        float h   = tg[s + 1] - tg[s];
        float srt = SIG * sqrtf(h);
        float sx = 0.f, sg = 0.f, sgn = 0.f;
        float grad[4], xcv[4], dwv[4];
        #pragma unroll
        for (int m = 0; m < 4; ++m) {
            int c = lane + 64 * m;
            float gsum = red[0][r][c] + red[1][r][c] + red[2][r][c] + red[3][r][c]
                       + b3[c];
            grad[m] = gsum;
            xcv[m]  = xc[row * DD + c];
            dwv[m]  = dWs[row * DD + c];
            float d = xcv[m] - law[c];
            sx  = fmaf(d, d, sx);
            sg  = fmaf(gsum, gsum, sg);
            sgn = fmaf(gsum, dwv[m], sgn);
        }
        #pragma unroll
        for (int off = 32; off >= 1; off >>= 1) {
            sx  += __shfl_xor(sx, off);
            sg  += __shfl_xor(sg, off);
            sgn += __shfl_xor(sgn, off);
        }
        if (lane == 0) {
            float f  = 0.5f * sx + 0.5f * sg;     // KAPPA = 1
            float vn = vv[row] - f * h + srt * sgn;
            vv[row] = vn;
            if (s == SS - 1) out[row] = vn;
        }
        #pragma unroll
        for (int m = 0; m < 4; ++m) {
            int c = lane + 64 * m;
            xc[row * DD + c] = xcv[m] - grad[m] * h + srt * dwv[m];
        }
    }
}

// ---------------- v0 layer 3: y3 = A2v @ Wv3 + bv3 (N=1) ----------------
__global__ __launch_bounds__(256) void k_v0l3(
    const float* __restrict__ y2, const float* __restrict__ stats_in,
    const float* __restrict__ gv, const float* __restrict__ bev,
    const float* __restrict__ wv3, const float* __restrict__ bv3,
    float* __restrict__ vout, float* __restrict__ sv)
{
    __shared__ float AC[2][HP];
    __shared__ float WC[HP];
    __shared__ float rv[16], rq[16];
    const int tid = threadIdx.x;

    compute_ac(stats_in, gv, bev, AC);
    for (int t = tid; t < HP; t += 256)
        WC[t] = (t < HH) ? wv3[t] : 0.0f;
    __syncthreads();

    const int r   = tid >> 4;      // 16 rows per block
    const int ks  = tid & 15;      // 16-way K split
    const int row = blockIdx.x * 16 + r;
    const int k0  = ks * 17;
    const int k1  = (k0 + 17 < HH) ? (k0 + 17) : HH;
    float acc = 0.0f;
    for (int k = k0; k < k1; ++k) {
        float y  = y2[row * HP + k];
        float a2 = fmaxf(fmaf(AC[0][k], y, AC[1][k]), 0.0f);
        acc = fmaf(a2, WC[k], acc);
    }
    acc += __shfl_xor(acc, 1);
    acc += __shfl_xor(acc, 2);
    acc += __shfl_xor(acc, 4);
    acc += __shfl_xor(acc, 8);
    if (ks == 0) {
        float y = acc + bv3[0];
        vout[row] = y;
        rv[r] = y;
        rq[r] = y * y;
    }
    __syncthreads();
    if (tid == 0) {
        float s = 0.f, q = 0.f;
        #pragma unroll
        for (int i = 0; i < 16; ++i) { s += rv[i]; q += rq[i]; }
        atomicAdd(sv, s);
        atomicAdd(sv + 1, q);
    }
}

// ---------------- v0 finalize: v = relu(BN(y3)) ----------------
__global__ __launch_bounds__(256) void k_v0fin(
    float* __restrict__ v, const float* __restrict__ sv,
    const float* __restrict__ gv3, const float* __restrict__ bev3)
{
    int row = blockIdx.x * 256 + threadIdx.x;
    float mu  = sv[0] * (1.0f / 2048.0f);
    float var = sv[1] * (1.0f / 2048.0f) - mu * mu;
    float rs  = rsqrtf(fmaxf(var, 0.0f) + BN_EPS);
    float y   = v[row];
    v[row] = fmaxf(gv3[0] * (y - mu) * rs + bev3[0], 0.0f);
}

extern "C" void kernel_launch(void* const* d_in, const int* in_sizes, int n_in,
                              void* d_out, int out_size, void* d_ws, size_t ws_size,
                              hipStream_t stream)
{
    (void)in_sizes; (void)n_in; (void)out_size; (void)ws_size;
    const float* x    = (const float*)d_in[0];
    const float* dW   = (const float*)d_in[1];
    const float* law  = (const float*)d_in[2];
    const float* tg   = (const float*)d_in[3];
    const float* W1   = (const float*)d_in[4];
    const float* b1   = (const float*)d_in[5];
    const float* g1   = (const float*)d_in[6];
    const float* be1  = (const float*)d_in[7];
    const float* W2   = (const float*)d_in[8];
    const float* b2   = (const float*)d_in[9];
    const float* g2   = (const float*)d_in[10];
    const float* be2  = (const float*)d_in[11];
    const float* W3   = (const float*)d_in[12];
    const float* b3   = (const float*)d_in[13];
    const float* Wv1  = (const float*)d_in[14];
    const float* bv1  = (const float*)d_in[15];
    const float* gv1  = (const float*)d_in[16];
    const float* bev1 = (const float*)d_in[17];
    const float* Wv2  = (const float*)d_in[18];
    const float* bv2  = (const float*)d_in[19];
    const float* gv2  = (const float*)d_in[20];
    const float* bev2 = (const float*)d_in[21];
    const float* Wv3  = (const float*)d_in[22];
    const float* bv3  = (const float*)d_in[23];
    const float* gv3  = (const float*)d_in[24];
    const float* bev3 = (const float*)d_in[25];

    float* ws = (float*)d_ws;
    float* xc = ws + XC_OFF;
    float* Y1 = ws + Y1_OFF;
    float* Y2 = ws + Y2_OFF;
    float* V  = ws + V_OFF;
    float* S1 = ws + S1_OFF;   // parity stride 4352
    float* S2 = ws + S2_OFF;
    float* SV = ws + SV_OFF;
    float* out = (float*)d_out;

    k_init<<<2117, 256, 0, stream>>>(x, ws);

    // v0 network (uses parity-1 stat buffers; main loop s=0 uses parity 0)
    k_gemm<<<1024, 256, 0, stream>>>(1, DD, x, DD, nullptr, nullptr, nullptr,
                                     Wv1, bv1, Y1, S1 + 4352, nullptr);
    k_gemm<<<1024, 256, 0, stream>>>(2, HH, Y1, HP, S1 + 4352, gv1, bev1,
                                     Wv2, bv2, Y2, S2 + 4352, nullptr);
    k_v0l3<<<128, 256, 0, stream>>>(Y2, S2 + 4352, gv2, bev2, Wv3, bv3, V, SV);
    k_v0fin<<<8, 256, 0, stream>>>(V, SV, gv3, bev3);

    for (int s = 0; s < SS; ++s) {
        int p = s & 1;
        k_gemm<<<1024, 256, 0, stream>>>(1, DD, xc, DD, nullptr, nullptr, nullptr,
                                         W1 + (size_t)s * DD * HH, b1 + s * HH, Y1,
                                         S1 + p * 4352, S1 + (1 - p) * 4352);
        k_gemm<<<1024, 256, 0, stream>>>(2, HH, Y1, HP, S1 + p * 4352,
                                         g1 + s * HH, be1 + s * HH,
                                         W2 + (size_t)s * HH * HH, b2 + s * HH, Y2,
                                         S2 + p * 4352, S2 + (1 - p) * 4352);
        k_step3<<<512, 256, 0, stream>>>(Y2, S2 + p * 4352,
                                         g2 + s * HH, be2 + s * HH,
                                         W3 + (size_t)s * HH * DD, b3 + s * DD,
                                         law + s * DD, dW + (size_t)s * BATCH * DD,
                                         tg, s, xc, V, out);
    }
}

// Round 3
// 2429.173 us; speedup vs baseline: 2.2731x; 2.2731x over previous
//
#include <hip/hip_runtime.h>
#include <hip/hip_bf16.h>

// B=2048, D=256, H=266 (pad N->272, K->288), S=50. All f32 I/O; bf16 MFMA inside.
// Per step: k_lin (P2: affine-relu GEMM + stats), k_fused (P3 grad GEMM + row
// update of v/xc + P1 GEMM of next step + stats). Weights pre-swizzled to
// MFMA B-fragment layout in ws (bf16) once per call.

#define BATCH 2048
#define DD    256
#define HH    266
#define HP    272
#define SS    50
#define BN_EPS 1e-5f
#define SIG   0.3f
#define AS_STRIDE 296   // LDS A-tile row stride in bf16 elements (16B-aligned, bank-spread)

// f32 workspace offsets
#define XC_OFF 0              // [2048][256]
#define Y1_OFF 524288         // [2048][272]
#define Y2_OFF 1081344        // [2048][272]
#define V_OFF  1638400        // [2048]
#define S1_OFF 1640448        // 2 parity x 8 reps x 544
#define S2_OFF 1649152
#define S1V_OFF 1657856       // 8 x 544
#define S2V_OFF 1662208
#define SV_OFF  1666560       // 16
#define WQ_OFF  1666576       // bf16 region starts here (x4 bytes, 16B aligned)

// swizzled weight strides (ushort units)
#define W1S 69632   // 8kt*17nt*512
#define W2S 78336   // 9*17*512
#define W3S 73728   // 9*16*512
#define W1Q_OFF 0
#define W2Q_OFF 3481600
#define W3Q_OFF 7398400
#define WV1Q_OFF 11084800
#define WV2Q_OFF 11154432

typedef unsigned short ushort_t;
using short8 = __attribute__((ext_vector_type(8))) short;
using f32x4  = __attribute__((ext_vector_type(4))) float;

__device__ __forceinline__ ushort_t f2b(float f) {   // f32 -> bf16 bits, RNE
    unsigned u = __float_as_uint(f);
    unsigned r = u + 0x7FFF + ((u >> 16) & 1);
    return (ushort_t)(r >> 16);
}

// ---------------- init: xc = x, zero stat buffers ----------------
__global__ __launch_bounds__(256) void k_init(const float* __restrict__ x,
                                              float* __restrict__ ws) {
    int idx = blockIdx.x * 256 + threadIdx.x;
    if (idx < BATCH * DD) {
        ws[XC_OFF + idx] = x[idx];
    } else {
        int z = idx - BATCH * DD;
        if (z < 26128) ws[S1_OFF + z] = 0.0f;  // S1,S2,S1v,S2v,SV
    }
}

// ---------------- weight swizzle: f32 [K][N] -> bf16 B-frag layout ----------------
__global__ __launch_bounds__(256) void k_conv(const float* __restrict__ src,
                                              ushort_t* __restrict__ dst,
                                              int K, int N, int KT, int NT,
                                              long total) {
    long t = (long)blockIdx.x * 256 + threadIdx.x;
    if (t >= total) return;
    int per = KT * NT * 512;
    int step = (int)(t / per);
    int e = (int)(t - (long)step * per);
    int kt = e / (NT * 512);
    int r = e - kt * NT * 512;
    int nt = r / 512;
    int r2 = r & 511;
    int lane = r2 >> 3;
    int j = r2 & 7;
    int k = kt * 32 + (lane >> 4) * 8 + j;
    int n = nt * 16 + (lane & 15);
    float v = (k < K && n < N) ? src[(size_t)step * K * N + (size_t)k * N + n] : 0.f;
    dst[t] = f2b(v);
}

// BN affine constants: A = relu(a*y + c)
__device__ __forceinline__ void compute_ac(const float* __restrict__ stats_in,
                                           const float* __restrict__ g,
                                           const float* __restrict__ be,
                                           float (*AC)[HP]) {
    for (int t = threadIdx.x; t < HP; t += 256) {
        float a = 0.f, c = 0.f;
        if (t < HH) {
            float s = 0.f, q = 0.f;
            #pragma unroll
            for (int r = 0; r < 8; ++r) {
                s += stats_in[r * 544 + t];
                q += stats_in[r * 544 + 272 + t];
            }
            float mu  = s * (1.0f / 2048.0f);
            float var = q * (1.0f / 2048.0f) - mu * mu;
            float rs  = rsqrtf(fmaxf(var, 0.0f) + BN_EPS);
            a = g[t] * rs;
            c = be[t] - mu * a;
        }
        AC[0][t] = a;
        AC[1][t] = c;
    }
}

// ---------------- k_lin: [affine-relu] GEMM (NT=17) + stats ----------------
// mode 0: raw f32 xsrc (K=KT*32); mode 2: affine(stats) on Y. Grid 256 (128 M x 2 N-halves).
__global__ __launch_bounds__(256) void k_lin(
    int mode, int KT, const float* __restrict__ xsrc, int xld,
    const float* __restrict__ stats_in, const float* __restrict__ g,
    const float* __restrict__ be,
    const ushort_t* __restrict__ Wq, const float* __restrict__ bias,
    float* __restrict__ yout, float* __restrict__ stats_out,
    float* __restrict__ zero_ptr)
{
    __shared__ ushort_t As[16 * AS_STRIDE];
    __shared__ float AC[2][HP];
    const int tid  = threadIdx.x;
    const int lane = tid & 63;
    const int wv   = tid >> 6;
    const int quad = lane >> 4;
    const int l15  = lane & 15;
    const int h    = blockIdx.x & 1;
    const int row0 = (blockIdx.x >> 1) * 16;

    if (zero_ptr != nullptr && blockIdx.x < 17)
        zero_ptr[blockIdx.x * 256 + tid] = 0.0f;

    if (mode == 2) { compute_ac(stats_in, g, be, AC); __syncthreads(); }

    const int PAIRS = KT * 16;
    for (int idx = tid; idx < 16 * PAIRS; idx += 256) {
        int m  = idx / PAIRS;
        int kk = (idx - m * PAIRS) * 2;
        float v0, v1;
        if (mode == 2) {
            v0 = (kk < HH)     ? fmaxf(fmaf(AC[0][kk],     xsrc[(size_t)(row0+m)*xld + kk],     AC[1][kk]),     0.f) : 0.f;
            v1 = (kk+1 < HH)   ? fmaxf(fmaf(AC[0][kk+1],   xsrc[(size_t)(row0+m)*xld + kk+1],   AC[1][kk+1]),   0.f) : 0.f;
        } else {
            v0 = xsrc[(size_t)(row0+m)*xld + kk];
            v1 = xsrc[(size_t)(row0+m)*xld + kk + 1];
        }
        ((unsigned int*)As)[m * (AS_STRIDE/2) + (kk >> 1)] =
            (unsigned int)f2b(v0) | ((unsigned int)f2b(v1) << 16);
    }
    __syncthreads();

    const int tbase = h ? 9 : 0;
    const int tlim  = h ? 17 : 9;
    f32x4 acc[3];
    #pragma unroll
    for (int i = 0; i < 3; ++i) acc[i] = (f32x4){0.f, 0.f, 0.f, 0.f};

    for (int kt = 0; kt < KT; ++kt) {
        short8 af = *(const short8*)(&As[l15 * AS_STRIDE + kt * 32 + quad * 8]);
        const ushort_t* wp = Wq + ((size_t)(kt * 17 + tbase + wv)) * 512 + lane * 8;
        #pragma unroll
        for (int i = 0; i < 3; ++i) {
            int t = tbase + wv + i * 4;
            if (t < tlim) {
                short8 bf = *(const short8*)(wp + (size_t)i * 4 * 512);
                acc[i] = __builtin_amdgcn_mfma_f32_16x16x32_bf16(af, bf, acc[i], 0, 0, 0);
            }
        }
    }

    #pragma unroll
    for (int i = 0; i < 3; ++i) {
        int t = tbase + wv + i * 4;
        if (t >= tlim) continue;
        int col = t * 16 + l15;
        float bj = (col < HH) ? bias[col] : 0.f;
        float y0 = acc[i][0] + bj, y1 = acc[i][1] + bj;
        float y2 = acc[i][2] + bj, y3 = acc[i][3] + bj;
        yout[(size_t)(row0 + quad*4 + 0) * HP + col] = y0;
        yout[(size_t)(row0 + quad*4 + 1) * HP + col] = y1;
        yout[(size_t)(row0 + quad*4 + 2) * HP + col] = y2;
        yout[(size_t)(row0 + quad*4 + 3) * HP + col] = y3;
        float sp = y0 + y1 + y2 + y3;
        float sq = y0*y0 + y1*y1 + y2*y2 + y3*y3;
        sp += __shfl_xor(sp, 16); sp += __shfl_xor(sp, 32);
        sq += __shfl_xor(sq, 16); sq += __shfl_xor(sq, 32);
        if (quad == 0 && col < HH) {
            float* spp = stats_out + (blockIdx.x & 7) * 544;
            atomicAdd(spp + col, sp);
            atomicAdd(spp + 272 + col, sq);
        }
    }
}

// ---------------- k_fused: P3 grad GEMM + v/xc update + P1(s+1) GEMM ----------------
// Grid 128 (16 rows/block, full N per block for row reductions).
__global__ __launch_bounds__(256) void k_fused(
    const float* __restrict__ y2g, const float* __restrict__ stats_in,
    const float* __restrict__ g2, const float* __restrict__ be2,
    const ushort_t* __restrict__ W3q, const float* __restrict__ b3,
    const float* __restrict__ law, const float* __restrict__ dWs,
    const float* __restrict__ tg, int s, int doP1,
    float* __restrict__ xc, float* __restrict__ vv, float* __restrict__ outv,
    const ushort_t* __restrict__ W1q, const float* __restrict__ b1n,
    float* __restrict__ Y1, float* __restrict__ stats_out,
    float* __restrict__ zero_ptr)
{
    __shared__ ushort_t As[16 * AS_STRIDE];
    __shared__ float AC[2][HP];
    __shared__ float red[4][4][4][3];   // [wave][quad][reg][sx,sg,sgn]
    const int tid  = threadIdx.x;
    const int lane = tid & 63;
    const int wv   = tid >> 6;
    const int quad = lane >> 4;
    const int l15  = lane & 15;
    const int row0 = blockIdx.x * 16;

    if (zero_ptr != nullptr && blockIdx.x < 17)
        zero_ptr[blockIdx.x * 256 + tid] = 0.0f;

    compute_ac(stats_in, g2, be2, AC);
    __syncthreads();

    // stage A2 = relu(affine(Y2)) into LDS, K padded to 288
    for (int idx = tid; idx < 16 * 144; idx += 256) {
        int m  = idx / 144;
        int kk = (idx - m * 144) * 2;
        float v0 = (kk < HH)   ? fmaxf(fmaf(AC[0][kk],   y2g[(size_t)(row0+m)*HP + kk],   AC[1][kk]),   0.f) : 0.f;
        float v1 = (kk+1 < HH) ? fmaxf(fmaf(AC[0][kk+1], y2g[(size_t)(row0+m)*HP + kk+1], AC[1][kk+1]), 0.f) : 0.f;
        ((unsigned int*)As)[m * (AS_STRIDE/2) + (kk >> 1)] =
            (unsigned int)f2b(v0) | ((unsigned int)f2b(v1) << 16);
    }
    __syncthreads();

    // P3 GEMM: KT=9, NT=16, wave wv owns tiles wv+4i
    f32x4 acc[4];
    #pragma unroll
    for (int i = 0; i < 4; ++i) acc[i] = (f32x4){0.f, 0.f, 0.f, 0.f};
    for (int kt = 0; kt < 9; ++kt) {
        short8 af = *(const short8*)(&As[l15 * AS_STRIDE + kt * 32 + quad * 8]);
        const ushort_t* wp = W3q + ((size_t)(kt * 16 + wv)) * 512 + lane * 8;
        #pragma unroll
        for (int i = 0; i < 4; ++i) {
            short8 bf = *(const short8*)(wp + (size_t)i * 4 * 512);
            acc[i] = __builtin_amdgcn_mfma_f32_16x16x32_bf16(af, bf, acc[i], 0, 0, 0);
        }
    }

    // epilogue: grad, row partials
    const float h   = tg[s + 1] - tg[s];
    const float srt = SIG * sqrtf(h);
    float grad[4][4], xcv[4][4], dwv[4][4];
    float sxr[4] = {0,0,0,0}, sgr[4] = {0,0,0,0}, sgnr[4] = {0,0,0,0};
    #pragma unroll
    for (int i = 0; i < 4; ++i) {
        int col = (wv + 4*i) * 16 + l15;
        #pragma unroll
        for (int r = 0; r < 4; ++r) {
            int row = row0 + quad * 4 + r;
            float gd = acc[i][r] + b3[col];
            float xv = xc[(size_t)row * DD + col];
            float dw = dWs[(size_t)row * DD + col];
            float d  = xv - law[col];
            grad[i][r] = gd; xcv[i][r] = xv; dwv[i][r] = dw;
            sxr[r]  = fmaf(d, d, sxr[r]);
            sgr[r]  = fmaf(gd, gd, sgr[r]);
            sgnr[r] = fmaf(gd, dw, sgnr[r]);
        }
    }
    #pragma unroll
    for (int off = 1; off < 16; off <<= 1) {
        #pragma unroll
        for (int r = 0; r < 4; ++r) {
            sxr[r]  += __shfl_xor(sxr[r],  off);
            sgr[r]  += __shfl_xor(sgr[r],  off);
            sgnr[r] += __shfl_xor(sgnr[r], off);
        }
    }
    if (l15 == 0) {
        #pragma unroll
        for (int r = 0; r < 4; ++r) {
            red[wv][quad][r][0] = sxr[r];
            red[wv][quad][r][1] = sgr[r];
            red[wv][quad][r][2] = sgnr[r];
        }
    }
    __syncthreads();   // red ready; also all waves done reading As

    if (wv == 0 && l15 == 0) {
        #pragma unroll
        for (int r = 0; r < 4; ++r) {
            int row = row0 + quad * 4 + r;
            float sx  = red[0][quad][r][0] + red[1][quad][r][0] + red[2][quad][r][0] + red[3][quad][r][0];
            float sg  = red[0][quad][r][1] + red[1][quad][r][1] + red[2][quad][r][1] + red[3][quad][r][1];
            float sgn = red[0][quad][r][2] + red[1][quad][r][2] + red[2][quad][r][2] + red[3][quad][r][2];
            float f  = 0.5f * (sx + sg);
            float vn = vv[row] - f * h + srt * sgn;
            vv[row] = vn;
            if (s == SS - 1) outv[row] = vn;
        }
    }

    // xc update (global) + stage new A1 into LDS (bf16)
    #pragma unroll
    for (int i = 0; i < 4; ++i) {
        int col = (wv + 4*i) * 16 + l15;
        #pragma unroll
        for (int r = 0; r < 4; ++r) {
            int row = row0 + quad * 4 + r;
            float xn = xcv[i][r] - grad[i][r] * h + srt * dwv[i][r];
            xc[(size_t)row * DD + col] = xn;
            if (doP1) As[(quad * 4 + r) * AS_STRIDE + col] = f2b(xn);
        }
    }
    if (!doP1) return;
    __syncthreads();

    // P1(s+1) GEMM: KT=8, NT=17, wave wv owns tiles wv+4i (i<5)
    f32x4 acc2[5];
    #pragma unroll
    for (int i = 0; i < 5; ++i) acc2[i] = (f32x4){0.f, 0.f, 0.f, 0.f};
    for (int kt = 0; kt < 8; ++kt) {
        short8 af = *(const short8*)(&As[l15 * AS_STRIDE + kt * 32 + quad * 8]);
        const ushort_t* wp = W1q + ((size_t)(kt * 17 + wv)) * 512 + lane * 8;
        #pragma unroll
        for (int i = 0; i < 5; ++i) {
            int t = wv + i * 4;
            if (t < 17) {
                short8 bf = *(const short8*)(wp + (size_t)i * 4 * 512);
                acc2[i] = __builtin_amdgcn_mfma_f32_16x16x32_bf16(af, bf, acc2[i], 0, 0, 0);
            }
        }
    }
    #pragma unroll
    for (int i = 0; i < 5; ++i) {
        int t = wv + i * 4;
        if (t >= 17) continue;
        int col = t * 16 + l15;
        float bj = (col < HH) ? b1n[col] : 0.f;
        float y0 = acc2[i][0] + bj, y1 = acc2[i][1] + bj;
        float y2 = acc2[i][2] + bj, y3 = acc2[i][3] + bj;
        Y1[(size_t)(row0 + quad*4 + 0) * HP + col] = y0;
        Y1[(size_t)(row0 + quad*4 + 1) * HP + col] = y1;
        Y1[(size_t)(row0 + quad*4 + 2) * HP + col] = y2;
        Y1[(size_t)(row0 + quad*4 + 3) * HP + col] = y3;
        float sp = y0 + y1 + y2 + y3;
        float sq = y0*y0 + y1*y1 + y2*y2 + y3*y3;
        sp += __shfl_xor(sp, 16); sp += __shfl_xor(sp, 32);
        sq += __shfl_xor(sq, 16); sq += __shfl_xor(sq, 32);
        if (quad == 0 && col < HH) {
            float* spp = stats_out + (blockIdx.x & 7) * 544;
            atomicAdd(spp + col, sp);
            atomicAdd(spp + 272 + col, sq);
        }
    }
}

// ---------------- v0 layer 3 (N=1) ----------------
__global__ __launch_bounds__(256) void k_v0l3(
    const float* __restrict__ y2, const float* __restrict__ stats_in,
    const float* __restrict__ gv, const float* __restrict__ bev,
    const float* __restrict__ wv3, const float* __restrict__ bv3,
    float* __restrict__ vout, float* __restrict__ sv)
{
    __shared__ float AC[2][HP];
    __shared__ float WC[HP];
    __shared__ float rv[16], rq[16];
    const int tid = threadIdx.x;

    compute_ac(stats_in, gv, bev, AC);
    for (int t = tid; t < HP; t += 256)
        WC[t] = (t < HH) ? wv3[t] : 0.0f;
    __syncthreads();

    const int r   = tid >> 4;
    const int ks  = tid & 15;
    const int row = blockIdx.x * 16 + r;
    const int k0  = ks * 17;
    const int k1  = (k0 + 17 < HH) ? (k0 + 17) : HH;
    float acc = 0.0f;
    for (int k = k0; k < k1; ++k) {
        float y  = y2[(size_t)row * HP + k];
        float a2 = fmaxf(fmaf(AC[0][k], y, AC[1][k]), 0.0f);
        acc = fmaf(a2, WC[k], acc);
    }
    acc += __shfl_xor(acc, 1);
    acc += __shfl_xor(acc, 2);
    acc += __shfl_xor(acc, 4);
    acc += __shfl_xor(acc, 8);
    if (ks == 0) {
        float y = acc + bv3[0];
        vout[row] = y;
        rv[r] = y;
        rq[r] = y * y;
    }
    __syncthreads();
    if (tid == 0) {
        float s = 0.f, q = 0.f;
        #pragma unroll
        for (int i = 0; i < 16; ++i) { s += rv[i]; q += rq[i]; }
        atomicAdd(sv, s);
        atomicAdd(sv + 1, q);
    }
}

__global__ __launch_bounds__(256) void k_v0fin(
    float* __restrict__ v, const float* __restrict__ sv,
    const float* __restrict__ gv3, const float* __restrict__ bev3)
{
    int row = blockIdx.x * 256 + threadIdx.x;
    float mu  = sv[0] * (1.0f / 2048.0f);
    float var = sv[1] * (1.0f / 2048.0f) - mu * mu;
    float rs  = rsqrtf(fmaxf(var, 0.0f) + BN_EPS);
    float y   = v[row];
    v[row] = fmaxf(gv3[0] * (y - mu) * rs + bev3[0], 0.0f);
}

extern "C" void kernel_launch(void* const* d_in, const int* in_sizes, int n_in,
                              void* d_out, int out_size, void* d_ws, size_t ws_size,
                              hipStream_t stream)
{
    (void)in_sizes; (void)n_in; (void)out_size; (void)ws_size;
    const float* x    = (const float*)d_in[0];
    const float* dW   = (const float*)d_in[1];
    const float* law  = (const float*)d_in[2];
    const float* tg   = (const float*)d_in[3];
    const float* W1   = (const float*)d_in[4];
    const float* b1   = (const float*)d_in[5];
    const float* g1   = (const float*)d_in[6];
    const float* be1  = (const float*)d_in[7];
    const float* W2   = (const float*)d_in[8];
    const float* b2   = (const float*)d_in[9];
    const float* g2   = (const float*)d_in[10];
    const float* be2  = (const float*)d_in[11];
    const float* W3   = (const float*)d_in[12];
    const float* b3   = (const float*)d_in[13];
    const float* Wv1  = (const float*)d_in[14];
    const float* bv1  = (const float*)d_in[15];
    const float* gv1  = (const float*)d_in[16];
    const float* bev1 = (const float*)d_in[17];
    const float* Wv2  = (const float*)d_in[18];
    const float* bv2  = (const float*)d_in[19];
    const float* gv2  = (const float*)d_in[20];
    const float* bev2 = (const float*)d_in[21];
    const float* Wv3  = (const float*)d_in[22];
    const float* bv3  = (const float*)d_in[23];
    const float* gv3  = (const float*)d_in[24];
    const float* bev3 = (const float*)d_in[25];

    float* ws = (float*)d_ws;
    float* xc  = ws + XC_OFF;
    float* Y1  = ws + Y1_OFF;
    float* Y2  = ws + Y2_OFF;
    float* V   = ws + V_OFF;
    float* S1  = ws + S1_OFF;
    float* S2  = ws + S2_OFF;
    float* S1v = ws + S1V_OFF;
    float* S2v = ws + S2V_OFF;
    float* SV  = ws + SV_OFF;
    ushort_t* WQ = (ushort_t*)(ws + WQ_OFF);
    ushort_t* W1q  = WQ + W1Q_OFF;
    ushort_t* W2q  = WQ + W2Q_OFF;
    ushort_t* W3q  = WQ + W3Q_OFF;
    ushort_t* Wv1q = WQ + WV1Q_OFF;
    ushort_t* Wv2q = WQ + WV2Q_OFF;
    float* out = (float*)d_out;

    k_init<<<2151, 256, 0, stream>>>(x, ws);
    k_conv<<<13600, 256, 0, stream>>>(W1,  W1q,  DD, HH, 8, 17, (long)SS * W1S);
    k_conv<<<15300, 256, 0, stream>>>(W2,  W2q,  HH, HH, 9, 17, (long)SS * W2S);
    k_conv<<<14400, 256, 0, stream>>>(W3,  W3q,  HH, DD, 9, 16, (long)SS * W3S);
    k_conv<<<272,   256, 0, stream>>>(Wv1, Wv1q, DD, HH, 8, 17, (long)W1S);
    k_conv<<<306,   256, 0, stream>>>(Wv2, Wv2q, HH, HH, 9, 17, (long)W2S);

    // v0 network
    k_lin<<<256, 256, 0, stream>>>(0, 8, x, DD, nullptr, nullptr, nullptr,
                                   Wv1q, bv1, Y1, S1v, nullptr);
    k_lin<<<256, 256, 0, stream>>>(2, 9, Y1, HP, S1v, gv1, bev1,
                                   Wv2q, bv2, Y2, S2v, nullptr);
    k_v0l3<<<128, 256, 0, stream>>>(Y2, S2v, gv2, bev2, Wv3, bv3, V, SV);
    k_v0fin<<<8, 256, 0, stream>>>(V, SV, gv3, bev3);

    // P1(0): xc == x
    k_lin<<<256, 256, 0, stream>>>(0, 8, x, DD, nullptr, nullptr, nullptr,
                                   W1q, b1, Y1, S1, nullptr);

    for (int s = 0; s < SS; ++s) {
        int p = s & 1;
        k_lin<<<256, 256, 0, stream>>>(2, 9, Y1, HP, S1 + p * 4352,
                                       g1 + s * HH, be1 + s * HH,
                                       W2q + (size_t)s * W2S, b2 + s * HH,
                                       Y2, S2 + p * 4352, S1 + (1 - p) * 4352);
        int sn = (s + 1 < SS) ? s + 1 : 0;   // dummy valid ptrs when doP1==0
        k_fused<<<128, 256, 0, stream>>>(Y2, S2 + p * 4352,
                                         g2 + s * HH, be2 + s * HH,
                                         W3q + (size_t)s * W3S, b3 + s * DD,
                                         law + s * DD, dW + (size_t)s * BATCH * DD,
                                         tg, s, (s < SS - 1) ? 1 : 0,
                                         xc, V, out,
                                         W1q + (size_t)sn * W1S, b1 + sn * HH,
                                         Y1, S1 + ((s + 1) & 1) * 4352,
                                         S2 + (1 - p) * 4352);
    }
}